// Round 2
// baseline (383.000 us; speedup 1.0000x reference)
//
#include <hip/hip_runtime.h>
#include <math.h>

// ---- problem constants ----
#define B   64
#define L   64
#define C   16
#define CHD 64
#define EMB 300
#define D   450       // EMB + 3*50
#define DP  480       // padded bf16 row stride
#define NT  (B*L)     // 4096 tokens per branch
#define NBH 128       // 2 branches * 64 batch

typedef short bf16x8 __attribute__((ext_vector_type(8)));
typedef float f32x4  __attribute__((ext_vector_type(4)));
typedef float f32x2  __attribute__((ext_vector_type(2)));
typedef unsigned short ushort_t;
typedef ushort_t us4 __attribute__((ext_vector_type(4)));

// ---------------- helpers ----------------
__device__ inline float wave_sum(float v) {
#pragma unroll
    for (int o = 32; o; o >>= 1) v += __shfl_xor(v, o, 64);
    return v;
}
__device__ inline ushort_t f2b(float f) {   // RNE float->bf16
    union { float f; unsigned u; } c; c.f = f;
    unsigned r = c.u + 0x7FFFu + ((c.u >> 16) & 1u);
    return (ushort_t)(r >> 16);
}

// ---------------- kernel 0: word embedding copy (vectorized, 8 tokens/block) ----------------
__global__ __launch_bounds__(256) void wordcopy_kernel(
    const int* __restrict__ q1, const int* __restrict__ q2,
    const float* __restrict__ word_emb, float* __restrict__ xout,
    ushort_t* __restrict__ xb16)
{
    const int tid  = threadIdx.x;
    const int base = blockIdx.x * 8;
#pragma unroll 1
    for (int c = tid; c < 8 * 75; c += 256) {
        const int t  = c / 75, d4 = c - t * 75;
        const int tok    = base + t;
        const int branch = tok >> 12;
        const int tokl   = tok & (NT - 1);
        const int w      = (branch ? q2 : q1)[tokl];
        const float4 v = *(const float4*)(word_emb + (size_t)w * EMB + d4 * 4);
        float* dst = xout + (size_t)tok * D + d4 * 4;
        *(f32x2*)dst       = (f32x2){v.x, v.y};
        *(f32x2*)(dst + 2) = (f32x2){v.z, v.w};
        us4 pk = { f2b(v.x), f2b(v.y), f2b(v.z), f2b(v.w) };
        *(us4*)(xb16 + (size_t)tok * DP + d4 * 4) = pk;
    }
    if (tid < 240) {   // zero-pad D..DP for 8 tokens
        const int t = tid / 30, k = tid - t * 30;
        xb16[(size_t)(base + t) * DP + D + k] = 0;
    }
}

// ---------------- prep: Wpad bf16 [160][320], bias160, char_emb bf16 ----------------
__global__ __launch_bounds__(256) void conv_prep_kernel(
    const float* __restrict__ w3, const float* __restrict__ b3,
    const float* __restrict__ w4, const float* __restrict__ b4,
    const float* __restrict__ w5, const float* __restrict__ b5,
    const float* __restrict__ char_emb,
    ushort_t* __restrict__ Wpad, float* __restrict__ bias160,
    ushort_t* __restrict__ ceb16)
{
    int idx = blockIdx.x * 256 + threadIdx.x;
    if (idx < 160 * 320) {
        int f = idx / 320, kd = idx - f * 320;
        int k = kd >> 6, d = kd & 63;
        float v = 0.f;
        if (f < 50)       { if (k < 3) v = w3[f * 192 + d * 3 + k]; }
        else if (f < 100) { if (k < 4) v = w4[(f - 50) * 256 + d * 4 + k]; }
        else if (f < 150) { v = w5[(f - 100) * 320 + d * 5 + k]; }
        Wpad[idx] = f2b(v);
    } else if (idx < 160 * 320 + 160) {
        int f = idx - 160 * 320;
        bias160[f] = (f < 50) ? b3[f] : (f < 100) ? b4[f - 50] : (f < 150) ? b5[f - 100] : 0.f;
    } else if (idx < 160 * 320 + 160 + 100 * 64) {
        int i = idx - (160 * 320 + 160);
        ceb16[i] = f2b(char_emb[i]);
    }
}

// ---------------- kernel 1: unified char conv via bf16 MFMA ----------------
// 8 tokens/block, grid 1024 (4 blocks/CU). B fragments read straight from L2 (no W LDS tile).
#define ESS 72
#define EST (20 * ESS)

__global__ __launch_bounds__(256) void conv_mfma_kernel(
    const int* __restrict__ q1c, const int* __restrict__ q2c,
    const ushort_t* __restrict__ ceb16,
    const ushort_t* __restrict__ Wpad, const float* __restrict__ bias160,
    float* __restrict__ xout, ushort_t* __restrict__ xb16)
{
    __shared__ ushort_t es[8 * EST];   // 23040 B

    const int tid  = threadIdx.x;
    const int wv   = tid >> 6;
    const int lane = tid & 63;
    const int ln   = lane & 15, quad = lane >> 4;
    const int tokbase = blockIdx.x * 8;

    // stage char-embedding rows for 8 tokens (gather by char id)
#pragma unroll
    for (int i = 0; i < 4; ++i) {
        int c = tid + i * 256;
        int row = c >> 3, part = c & 7;
        int tl = row >> 4, cr = row & 15;
        int gtok   = tokbase + tl;
        int branch = gtok >> 12;
        int tokl   = gtok & (NT - 1);
        int cid    = (branch ? q2c : q1c)[tokl * C + cr];
        *(bf16x8*)&es[tl * EST + cr * ESS + part * 8] =
            *(const bf16x8*)&ceb16[cid * 64 + part * 8];
    }
    {   // zero the 4 pad rows per token
        int tl = tid >> 5, rr = (tid >> 3) & 3, part = tid & 7;
        bf16x8 z = {0, 0, 0, 0, 0, 0, 0, 0};
        *(bf16x8*)&es[tl * EST + (16 + rr) * ESS + part * 8] = z;
    }
    __syncthreads();

    const int t0 = wv * 2, t1 = t0 + 1;
    f32x4 acc[2][10];
#pragma unroll
    for (int t = 0; t < 2; ++t)
#pragma unroll
        for (int nt = 0; nt < 10; ++nt) acc[t][nt] = (f32x4){0.f, 0.f, 0.f, 0.f};

#pragma unroll 1
    for (int ks = 0; ks < 10; ++ks) {
        const int kk   = ks * 32 + quad * 8;
        const int arow = kk >> 6, aoff = kk & 63;
        bf16x8 a0 = *(const bf16x8*)&es[t0 * EST + (ln + arow) * ESS + aoff];
        bf16x8 a1 = *(const bf16x8*)&es[t1 * EST + (ln + arow) * ESS + aoff];
#pragma unroll
        for (int nt = 0; nt < 10; ++nt) {
            bf16x8 bf = *(const bf16x8*)&Wpad[(size_t)(nt * 16 + ln) * 320 + kk];
            acc[0][nt] = __builtin_amdgcn_mfma_f32_16x16x32_bf16(a0, bf, acc[0][nt], 0, 0, 0);
            acc[1][nt] = __builtin_amdgcn_mfma_f32_16x16x32_bf16(a1, bf, acc[1][nt], 0, 0, 0);
        }
    }

#pragma unroll
    for (int t = 0; t < 2; ++t) {
        const int gtok = tokbase + t0 + t;
#pragma unroll
        for (int nt = 0; nt < 10; ++nt) {
            const int f  = nt * 16 + ln;
            const int Pf = (f < 50) ? 14 : (f < 100) ? 13 : 12;
            float m = -1e30f;
#pragma unroll
            for (int r = 0; r < 4; ++r) {
                const int p = quad * 4 + r;
                if (p < Pf) m = fmaxf(m, acc[t][nt][r]);
            }
            m = fmaxf(m, __shfl_xor(m, 16, 64));
            m = fmaxf(m, __shfl_xor(m, 32, 64));
            if (quad == 0 && f < 150) {
                float rv = fmaxf(0.f, m + bias160[f]);
                xout[(size_t)gtok * D + EMB + f] = rv;
                xb16[(size_t)gtok * DP + EMB + f] = f2b(rv);
            }
        }
    }
}

// ---------------- kernel 1b: highway W -> bf16 padded image ----------------
__global__ __launch_bounds__(256) void wconv_kernel(
    const float* __restrict__ W, ushort_t* __restrict__ Wb16)
{
    int idx = blockIdx.x * 256 + threadIdx.x;
    if (idx >= 512 * DP) return;
    int n = idx / DP, k = idx - n * DP;
    float v = (n < D && k < D) ? W[(size_t)n * D + k] : 0.f;
    Wb16[idx] = f2b(v);
}

// ---------------- kernel 2: highway via bf16 MFMA (no LDS, XCD-affine grid) ----------------
// 1024 blocks 1-D; all 8 n-blocks of an m-panel land on one XCD so the A panel stays in its L2.
__global__ __launch_bounds__(256) void highway_mfma_kernel(
    const ushort_t* __restrict__ xb16, const float* __restrict__ xf32,
    const ushort_t* __restrict__ Wb16, const float* __restrict__ bvec,
    float* __restrict__ out, ushort_t* __restrict__ outb16)
{
    const int bx = blockIdx.x;
    const int cx = bx & 7, rr = bx >> 3;        // cx = XCD (dispatch round-robin)
    const int my = cx * 16 + (rr & 15);         // 16 m-panels per XCD
    const int mx = rr >> 4;                     // 8 n-panels, same XCD for fixed my

    const int tid  = threadIdx.x;
    const int wv   = tid >> 6;
    const int lane = tid & 63;
    const int wm = wv >> 1, wn = wv & 1;
    const int m0 = my * 64 + wm * 32;
    const int n0 = mx * 64 + wn * 32;
    const int lm = lane & 15, quad = lane >> 4;

    const ushort_t* ax = xb16 + (size_t)(m0 + lm) * DP + quad * 8;
    const ushort_t* bw = Wb16 + (size_t)(n0 + lm) * DP + quad * 8;

    f32x4 acc[2][2];
#pragma unroll
    for (int i = 0; i < 2; ++i)
#pragma unroll
        for (int j = 0; j < 2; ++j) acc[i][j] = (f32x4){0.f, 0.f, 0.f, 0.f};

#pragma unroll 1
    for (int k0 = 0; k0 < DP; k0 += 32) {
        bf16x8 a0 = *(const bf16x8*)(ax + k0);
        bf16x8 a1 = *(const bf16x8*)(ax + (size_t)16 * DP + k0);
        bf16x8 b0 = *(const bf16x8*)(bw + k0);
        bf16x8 b1 = *(const bf16x8*)(bw + (size_t)16 * DP + k0);
        acc[0][0] = __builtin_amdgcn_mfma_f32_16x16x32_bf16(a0, b0, acc[0][0], 0, 0, 0);
        acc[0][1] = __builtin_amdgcn_mfma_f32_16x16x32_bf16(a0, b1, acc[0][1], 0, 0, 0);
        acc[1][0] = __builtin_amdgcn_mfma_f32_16x16x32_bf16(a1, b0, acc[1][0], 0, 0, 0);
        acc[1][1] = __builtin_amdgcn_mfma_f32_16x16x32_bf16(a1, b1, acc[1][1], 0, 0, 0);
    }

#pragma unroll
    for (int nt = 0; nt < 2; ++nt) {
        const int n = n0 + nt * 16 + lm;
        const bool nval = (n < D);
        const float bv = nval ? bvec[n] : 0.f;
#pragma unroll
        for (int mt = 0; mt < 2; ++mt) {
#pragma unroll
            for (int r = 0; r < 4; ++r) {
                const int m = m0 + mt * 16 + quad * 4 + r;
                float y = acc[mt][nt][r] + bv;
                float g = 1.f / (1.f + __expf(-y));
                float o = 0.f;
                if (nval) {
                    float xo = xf32[(size_t)m * D + n];
                    o = g * fmaxf(y, 0.f) + (1.f - g) * xo;
                    out[(size_t)m * D + n] = o;
                }
                if (n < DP)
                    outb16[(size_t)m * DP + n] = f2b(nval ? o : 0.f);
            }
        }
    }
}

// ---------------- kernel 3a: attention prep (16 j-rows/block, grid 512) ----------------
#define PXS 496   // LDS row stride for transpose tile (16B-aligned rows)

__global__ __launch_bounds__(256) void attn_prep_kernel(
    const float* __restrict__ xf32, const ushort_t* __restrict__ xb16,
    const float* __restrict__ attn_w, int layer,
    ushort_t* __restrict__ xw3, ushort_t* __restrict__ xT,
    float* __restrict__ s1g, float* __restrict__ s2g)
{
    __shared__ ushort_t Xs[16 * PXS];   // 15872 B

    const int bx = blockIdx.x;
    const int bh = bx >> 2, jq = bx & 3;
    const int tid = threadIdx.x;
    const int wv  = tid >> 6;
    const int lane = tid & 63;
    const size_t tok0 = (size_t)bh * 64 + jq * 16;

    const float* wb = attn_w + (size_t)layer * 3 * D;   // w1 | w2 | w3
    const float* w3 = wb + 2 * D;

    // stage bf16 rows into LDS + emit xw3 (from f32)
#pragma unroll 1
    for (int c = tid; c < 16 * 60; c += 256) {
        const int j  = c / 60, k8 = c - j * 60;
        const int k0 = k8 * 8;
        bf16x8 v = *(const bf16x8*)&xb16[(tok0 + j) * DP + k0];
        *(bf16x8*)&Xs[j * PXS + k0] = v;
        const float* xr = xf32 + (tok0 + j) * D;
        bf16x8 pk;
#pragma unroll
        for (int t = 0; t < 8; ++t) {
            const int k = k0 + t;
            float p = (k < D) ? xr[k] * w3[k] : 0.f;
            pk[t] = (short)f2b(p);
        }
        *(bf16x8*)&xw3[(tok0 + j) * DP + k0] = pk;
    }

    // s1/s2 dots: 4 rows per wave
#pragma unroll 1
    for (int rr = 0; rr < 4; ++rr) {
        const int j = wv * 4 + rr;
        const float* xr = xf32 + (tok0 + j) * D;
        float a1 = 0.f, a2 = 0.f;
#pragma unroll
        for (int t = 0; t < 8; ++t) {
            const int k = lane + t * 64;
            if (k < D) {
                float xv = xr[k];
                a1 = fmaf(xv, wb[k], a1);
                a2 = fmaf(xv, wb[D + k], a2);
            }
        }
        a1 = wave_sum(a1);
        a2 = wave_sum(a2);
        if (lane == 0) { s1g[tok0 + j] = a1; s2g[tok0 + j] = a2; }
    }
    __syncthreads();

    // transposed emit: packed u32 (two j per word, two d rows per iter)
#pragma unroll 1
    for (int c = tid; c < 240 * 8; c += 256) {
        const int d2 = c >> 3, jp = (c & 7) * 2;
        unsigned r0 = *(const unsigned*)&Xs[jp * PXS + d2 * 2];
        unsigned r1 = *(const unsigned*)&Xs[(jp + 1) * PXS + d2 * 2];
        unsigned lo = (r0 & 0xFFFFu) | (r1 << 16);
        unsigned hi = (r0 >> 16) | (r1 & 0xFFFF0000u);
        ushort_t* dst = xT + ((size_t)bh * 480 + d2 * 2) * 64 + jq * 16 + jp;
        *(unsigned*)dst        = lo;
        *(unsigned*)(dst + 64) = hi;
    }
}

// ---------------- kernel 3b: attention core (tiny LDS, grid 512) ----------------
#define ALS 72    // P LDS row stride (bf16)

template <bool RES_EMIT>
__global__ __launch_bounds__(256) void attn_fused_kernel(
    const float* __restrict__ xf32, const ushort_t* __restrict__ xb16,
    const ushort_t* __restrict__ xw3, const ushort_t* __restrict__ xT,
    const float* __restrict__ s1g, const float* __restrict__ s2g,
    const int* __restrict__ q1_len, const int* __restrict__ q2_len,
    const float* __restrict__ attn_b, int layer,
    float* __restrict__ outf, ushort_t* __restrict__ outb16)
{
    __shared__ float    sc[16][68];   // masked scores, 4352 B
    __shared__ ushort_t Al[16 * ALS]; // P (bf16), 2304 B

    // XCD swizzle: 4 sibling blocks of one bh share an XCD's L2 (512 % 8 == 0).
    const int bx  = blockIdx.x;
    const int wid = (bx & 7) * 64 + (bx >> 3);
    const int bh  = wid >> 2, iq = wid & 3;
    const int branch = bh >> 6, b = bh & 63;
    const int tid  = threadIdx.x;
    const int wv   = tid >> 6;
    const int lane = tid & 63;
    const int ln   = lane & 15, quad = lane >> 4;
    const int i0   = iq * 16;

    // ---- QK^T: wave wv computes scores[16 i][16 j] for j-tile wv ----
    const ushort_t* xa = xb16 + ((size_t)bh * 64 + i0 + ln) * DP + quad * 8;
    const ushort_t* xb = xw3  + ((size_t)bh * 64 + wv * 16 + ln) * DP + quad * 8;

    f32x4 qacc = (f32x4){0.f, 0.f, 0.f, 0.f};
#pragma unroll
    for (int ks = 0; ks < 15; ++ks) {
        bf16x8 a  = *(const bf16x8*)(xa + ks * 32);
        bf16x8 bq = *(const bf16x8*)(xb + ks * 32);
        qacc = __builtin_amdgcn_mfma_f32_16x16x32_bf16(a, bq, qacc, 0, 0, 0);
    }

    const int   len  = (branch ? q2_len : q1_len)[b];
    const float bias = attn_b[layer];
    const int   j    = wv * 16 + ln;
    const float s2v  = s2g[bh * 64 + j];
#pragma unroll
    for (int reg = 0; reg < 4; ++reg) {
        const int i = i0 + quad * 4 + reg;
        float v = qacc[reg] + s1g[bh * 64 + i] + s2v + bias;
        if (j >= len) v = -1e-9f;        // reference's (buggy) mask value
        sc[quad * 4 + reg][j] = v;
    }
    __syncthreads();

    // ---- softmax: wave wv handles local rows wv*4..wv*4+3, full 64-lane row ----
#pragma unroll
    for (int rr = 0; rr < 4; ++rr) {
        const int r = wv * 4 + rr;
        float v = sc[r][lane];
        float m = v;
#pragma unroll
        for (int o = 32; o; o >>= 1) m = fmaxf(m, __shfl_xor(m, o, 64));
        float ev = __expf(v - m);
        float sm = ev;
#pragma unroll
        for (int o = 32; o; o >>= 1) sm += __shfl_xor(sm, o, 64);
        Al[r * ALS + lane] = f2b(ev * (1.f / sm));
    }
    __syncthreads();

    // ---- AV: out[i][d] = sum_j P[i][j] X[j][d]; d-tiles round-robin over waves ----
    const ushort_t* xTb = xT + (size_t)bh * 480 * 64;
    bf16x8 af0 = *(const bf16x8*)&Al[ln * ALS + quad * 8];
    bf16x8 af1 = *(const bf16x8*)&Al[ln * ALS + quad * 8 + 32];

#pragma unroll 1
    for (int dt = wv; dt < 30; dt += 4) {
        bf16x8 b0 = *(const bf16x8*)&xTb[(size_t)(dt * 16 + ln) * 64 + quad * 8];
        bf16x8 b1 = *(const bf16x8*)&xTb[(size_t)(dt * 16 + ln) * 64 + quad * 8 + 32];
        f32x4 acc = (f32x4){0.f, 0.f, 0.f, 0.f};
        acc = __builtin_amdgcn_mfma_f32_16x16x32_bf16(af0, b0, acc, 0, 0, 0);
        acc = __builtin_amdgcn_mfma_f32_16x16x32_bf16(af1, b1, acc, 0, 0, 0);

        const int d = dt * 16 + ln;
        if (d < D) {
#pragma unroll
            for (int reg = 0; reg < 4; ++reg) {
                const int i = i0 + quad * 4 + reg;
                float v = acc[reg];
                if (RES_EMIT) v += xf32[((size_t)bh * 64 + i) * D + d];
                outf[((size_t)bh * 64 + i) * D + d] = v;
                if (RES_EMIT)
                    outb16[((size_t)bh * 64 + i) * DP + d] = f2b(v);
            }
        }
    }
}

// ---------------- launch ----------------
extern "C" void kernel_launch(void* const* d_in, const int* in_sizes, int n_in,
                              void* d_out, int out_size, void* d_ws, size_t ws_size,
                              hipStream_t stream) {
    const int*   q1       = (const int*)  d_in[0];
    const int*   q2       = (const int*)  d_in[1];
    const int*   q1_len   = (const int*)  d_in[2];
    const int*   q2_len   = (const int*)  d_in[3];
    const int*   q1c      = (const int*)  d_in[4];
    const int*   q2c      = (const int*)  d_in[5];
    const float* word_emb = (const float*)d_in[6];
    const float* char_emb = (const float*)d_in[7];
    const float* w3       = (const float*)d_in[8];
    const float* b3       = (const float*)d_in[9];
    const float* w4       = (const float*)d_in[10];
    const float* b4       = (const float*)d_in[11];
    const float* w5       = (const float*)d_in[12];
    const float* b5       = (const float*)d_in[13];
    const float* hw_w     = (const float*)d_in[14];
    const float* hw_b     = (const float*)d_in[15];
    const float* attn_w   = (const float*)d_in[16];
    const float* attn_b   = (const float*)d_in[17];
    float* out = (float*)d_out;

    float*    buf0    = (float*)d_ws;                          // 2*NT*D f32
    float*    buf1    = buf0 + (size_t)2 * NT * D;             // 2*NT*D f32
    float*    bias160 = buf1 + (size_t)2 * NT * D;             // 160 f32
    ushort_t* xb16a   = (ushort_t*)(bias160 + 160);            // 2*NT*DP bf16
    ushort_t* xb16b   = xb16a + (size_t)2 * NT * DP;           // 2*NT*DP bf16
    ushort_t* Wb16    = xb16b + (size_t)2 * NT * DP;           // 512*DP bf16
    ushort_t* Wpad    = Wb16 + (size_t)512 * DP;               // 160*320 bf16
    ushort_t* ceb16   = Wpad + (size_t)160 * 320;              // 100*64 bf16
    ushort_t* xw3     = ceb16 + (size_t)100 * 64;              // 2*NT*DP bf16
    ushort_t* xTb     = xw3 + (size_t)2 * NT * DP;             // 128*480*64 bf16 (== 2*NT*DP)
    float*    s1g     = (float*)(xTb + (size_t)2 * NT * DP);   // 2*NT f32
    float*    s2g     = s1g + (size_t)2 * NT;                  // 2*NT f32

    // 1. prep + embeddings + conv -> buf0 f32 + xb16a
    conv_prep_kernel<<<226, 256, 0, stream>>>(w3, b3, w4, b4, w5, b5, char_emb,
                                              Wpad, bias160, ceb16);
    wconv_kernel<<<(512 * DP + 255) / 256, 256, 0, stream>>>(hw_w, Wb16);
    wordcopy_kernel<<<2 * NT / 8, 256, 0, stream>>>(q1, q2, word_emb, buf0, xb16a);
    conv_mfma_kernel<<<1024, 256, 0, stream>>>(q1c, q2c, ceb16, Wpad, bias160, buf0, xb16a);

    // 2. highway x2 via MFMA (XCD-affine 1-D grid)
    highway_mfma_kernel<<<1024, 256, 0, stream>>>(xb16a, buf0, Wb16, hw_b, buf1, xb16b);
    highway_mfma_kernel<<<1024, 256, 0, stream>>>(xb16b, buf1, Wb16, hw_b, buf0, xb16a);

    // 3. attn layer 0: prep from buf0/xb16a, core -> buf1/xb16b (residual fused)
    attn_prep_kernel<<<512, 256, 0, stream>>>(buf0, xb16a, attn_w, 0, xw3, xTb, s1g, s2g);
    attn_fused_kernel<true><<<512, 256, 0, stream>>>(
        buf0, xb16a, xw3, xTb, s1g, s2g, q1_len, q2_len, attn_b, 0, buf1, xb16b);

    // 4. attn layer 1: prep from buf1/xb16b, core -> d_out (f32 only)
    attn_prep_kernel<<<512, 256, 0, stream>>>(buf1, xb16b, attn_w, 1, xw3, xTb, s1g, s2g);
    attn_fused_kernel<false><<<512, 256, 0, stream>>>(
        buf1, xb16b, xw3, xTb, s1g, s2g, q1_len, q2_len, attn_b, 1, out, nullptr);
}

// Round 3
// 372.369 us; speedup vs baseline: 1.0285x; 1.0285x over previous
//
#include <hip/hip_runtime.h>
#include <math.h>

// ---- problem constants ----
#define B   64
#define L   64
#define C   16
#define CHD 64
#define EMB 300
#define D   450       // EMB + 3*50
#define DP  480       // padded bf16 row stride
#define NT  (B*L)     // 4096 tokens per branch
#define NBH 128       // 2 branches * 64 batch

typedef short bf16x8 __attribute__((ext_vector_type(8)));
typedef float f32x4  __attribute__((ext_vector_type(4)));
typedef float f32x2  __attribute__((ext_vector_type(2)));
typedef unsigned short ushort_t;
typedef ushort_t us4 __attribute__((ext_vector_type(4)));

// ---------------- helpers ----------------
__device__ inline float wave_sum(float v) {
#pragma unroll
    for (int o = 32; o; o >>= 1) v += __shfl_xor(v, o, 64);
    return v;
}
__device__ inline ushort_t f2b(float f) {   // RNE float->bf16
    union { float f; unsigned u; } c; c.f = f;
    unsigned r = c.u + 0x7FFFu + ((c.u >> 16) & 1u);
    return (ushort_t)(r >> 16);
}

// ---------------- kernel P: fused weight prep (wconv + conv_prep) ----------------
// region 1: Wb16 [512][DP]; region 2: Wpad/bias160/ceb16.
__global__ __launch_bounds__(256) void prep_kernel(
    const float* __restrict__ W,                                 // highway weight
    const float* __restrict__ w3, const float* __restrict__ b3,
    const float* __restrict__ w4, const float* __restrict__ b4,
    const float* __restrict__ w5, const float* __restrict__ b5,
    const float* __restrict__ char_emb,
    ushort_t* __restrict__ Wb16,
    ushort_t* __restrict__ Wpad, float* __restrict__ bias160,
    ushort_t* __restrict__ ceb16)
{
    int idx = blockIdx.x * 256 + threadIdx.x;
    if (idx < 512 * DP) {
        int n = idx / DP, k = idx - n * DP;
        float v = (n < D && k < D) ? W[(size_t)n * D + k] : 0.f;
        Wb16[idx] = f2b(v);
        return;
    }
    idx -= 512 * DP;
    if (idx < 160 * 320) {
        int f = idx / 320, kd = idx - f * 320;
        int k = kd >> 6, d = kd & 63;
        float v = 0.f;
        if (f < 50)       { if (k < 3) v = w3[f * 192 + d * 3 + k]; }
        else if (f < 100) { if (k < 4) v = w4[(f - 50) * 256 + d * 4 + k]; }
        else if (f < 150) { v = w5[(f - 100) * 320 + d * 5 + k]; }
        Wpad[idx] = f2b(v);
    } else if (idx < 160 * 320 + 160) {
        int f = idx - 160 * 320;
        bias160[f] = (f < 50) ? b3[f] : (f < 100) ? b4[f - 50] : (f < 150) ? b5[f - 100] : 0.f;
    } else if (idx < 160 * 320 + 160 + 100 * 64) {
        int i = idx - (160 * 320 + 160);
        ceb16[i] = f2b(char_emb[i]);
    }
}

// ---------------- kernel 1: fused word-embed copy + char conv (XCD-affine tokens) ----------------
#define ESS 72
#define EST (20 * ESS)

__global__ __launch_bounds__(256) void embed_conv_kernel(
    const int* __restrict__ q1, const int* __restrict__ q2,
    const int* __restrict__ q1c, const int* __restrict__ q2c,
    const float* __restrict__ word_emb, const ushort_t* __restrict__ ceb16,
    const ushort_t* __restrict__ Wpad, const float* __restrict__ bias160,
    float* __restrict__ xout, ushort_t* __restrict__ xb16)
{
    __shared__ ushort_t es[8 * EST];   // 23040 B

    const int tid  = threadIdx.x;
    const int wv   = tid >> 6;
    const int lane = tid & 63;
    const int ln   = lane & 15, quad = lane >> 4;
    const int bx   = blockIdx.x;
    // XCD-affine: XCD c owns tokens [c*1024, (c+1)*1024) -> bh in [c*16,(c+1)*16)
    const int tokbase = ((bx & 7) * 128 + (bx >> 3)) * 8;

    // ---- stage char-embedding rows for 8 tokens (gather by char id) ----
#pragma unroll
    for (int i = 0; i < 4; ++i) {
        int c = tid + i * 256;
        int row = c >> 3, part = c & 7;
        int tl = row >> 4, cr = row & 15;
        int gtok   = tokbase + tl;
        int branch = gtok >> 12;
        int tokl   = gtok & (NT - 1);
        int cid    = (branch ? q2c : q1c)[tokl * C + cr];
        *(bf16x8*)&es[tl * EST + cr * ESS + part * 8] =
            *(const bf16x8*)&ceb16[cid * 64 + part * 8];
    }
    {   // zero the 4 pad rows per token
        int tl = tid >> 5, rr = (tid >> 3) & 3, part = tid & 7;
        bf16x8 z = {0, 0, 0, 0, 0, 0, 0, 0};
        *(bf16x8*)&es[tl * EST + (16 + rr) * ESS + part * 8] = z;
    }

    // ---- word-embedding copy for the same 8 tokens (overlaps gather latency) ----
#pragma unroll 1
    for (int c = tid; c < 8 * 75; c += 256) {
        const int t  = c / 75, d4 = c - t * 75;
        const int tok    = tokbase + t;
        const int branch = tok >> 12;
        const int tokl   = tok & (NT - 1);
        const int w      = (branch ? q2 : q1)[tokl];
        const float4 v = *(const float4*)(word_emb + (size_t)w * EMB + d4 * 4);
        float* dst = xout + (size_t)tok * D + d4 * 4;
        *(f32x2*)dst       = (f32x2){v.x, v.y};
        *(f32x2*)(dst + 2) = (f32x2){v.z, v.w};
        us4 pk = { f2b(v.x), f2b(v.y), f2b(v.z), f2b(v.w) };
        *(us4*)(xb16 + (size_t)tok * DP + d4 * 4) = pk;
    }
    if (tid < 240) {   // zero-pad D..DP for 8 tokens
        const int t = tid / 30, k = tid - t * 30;
        xb16[(size_t)(tokbase + t) * DP + D + k] = 0;
    }
    __syncthreads();

    // ---- conv via MFMA ----
    const int t0 = wv * 2, t1 = t0 + 1;
    f32x4 acc[2][10];
#pragma unroll
    for (int t = 0; t < 2; ++t)
#pragma unroll
        for (int nt = 0; nt < 10; ++nt) acc[t][nt] = (f32x4){0.f, 0.f, 0.f, 0.f};

#pragma unroll 1
    for (int ks = 0; ks < 10; ++ks) {
        const int kk   = ks * 32 + quad * 8;
        const int arow = kk >> 6, aoff = kk & 63;
        bf16x8 a0 = *(const bf16x8*)&es[t0 * EST + (ln + arow) * ESS + aoff];
        bf16x8 a1 = *(const bf16x8*)&es[t1 * EST + (ln + arow) * ESS + aoff];
#pragma unroll
        for (int nt = 0; nt < 10; ++nt) {
            bf16x8 bf = *(const bf16x8*)&Wpad[(size_t)(nt * 16 + ln) * 320 + kk];
            acc[0][nt] = __builtin_amdgcn_mfma_f32_16x16x32_bf16(a0, bf, acc[0][nt], 0, 0, 0);
            acc[1][nt] = __builtin_amdgcn_mfma_f32_16x16x32_bf16(a1, bf, acc[1][nt], 0, 0, 0);
        }
    }

#pragma unroll
    for (int t = 0; t < 2; ++t) {
        const int gtok = tokbase + t0 + t;
#pragma unroll
        for (int nt = 0; nt < 10; ++nt) {
            const int f  = nt * 16 + ln;
            const int Pf = (f < 50) ? 14 : (f < 100) ? 13 : 12;
            float m = -1e30f;
#pragma unroll
            for (int r = 0; r < 4; ++r) {
                const int p = quad * 4 + r;
                if (p < Pf) m = fmaxf(m, acc[t][nt][r]);
            }
            m = fmaxf(m, __shfl_xor(m, 16, 64));
            m = fmaxf(m, __shfl_xor(m, 32, 64));
            if (quad == 0 && f < 150) {
                float rv = fmaxf(0.f, m + bias160[f]);
                xout[(size_t)gtok * D + EMB + f] = rv;
                xb16[(size_t)gtok * DP + EMB + f] = f2b(rv);
            }
        }
    }
}

// ---------------- kernel 2: highway via bf16 MFMA (no LDS, XCD-affine grid) ----------------
// launch_bounds(256,4): <=128 VGPR -> 4 blocks/CU -> clean single-round 1024-block dispatch.
__global__ __launch_bounds__(256, 4) void highway_mfma_kernel(
    const ushort_t* __restrict__ xb16, const float* __restrict__ xf32,
    const ushort_t* __restrict__ Wb16, const float* __restrict__ bvec,
    float* __restrict__ out, ushort_t* __restrict__ outb16)
{
    const int bx = blockIdx.x;
    const int cx = bx & 7, rr = bx >> 3;        // cx = XCD (dispatch round-robin)
    const int my = cx * 16 + (rr & 15);         // 16 m-panels per XCD
    const int mx = rr >> 4;                     // 8 n-panels, same XCD for fixed my

    const int tid  = threadIdx.x;
    const int wv   = tid >> 6;
    const int lane = tid & 63;
    const int wm = wv >> 1, wn = wv & 1;
    const int m0 = my * 64 + wm * 32;
    const int n0 = mx * 64 + wn * 32;
    const int lm = lane & 15, quad = lane >> 4;

    const ushort_t* ax = xb16 + (size_t)(m0 + lm) * DP + quad * 8;
    const ushort_t* bw = Wb16 + (size_t)(n0 + lm) * DP + quad * 8;

    f32x4 acc[2][2];
#pragma unroll
    for (int i = 0; i < 2; ++i)
#pragma unroll
        for (int j = 0; j < 2; ++j) acc[i][j] = (f32x4){0.f, 0.f, 0.f, 0.f};

#pragma unroll 3
    for (int k0 = 0; k0 < DP; k0 += 32) {
        bf16x8 a0 = *(const bf16x8*)(ax + k0);
        bf16x8 a1 = *(const bf16x8*)(ax + (size_t)16 * DP + k0);
        bf16x8 b0 = *(const bf16x8*)(bw + k0);
        bf16x8 b1 = *(const bf16x8*)(bw + (size_t)16 * DP + k0);
        acc[0][0] = __builtin_amdgcn_mfma_f32_16x16x32_bf16(a0, b0, acc[0][0], 0, 0, 0);
        acc[0][1] = __builtin_amdgcn_mfma_f32_16x16x32_bf16(a0, b1, acc[0][1], 0, 0, 0);
        acc[1][0] = __builtin_amdgcn_mfma_f32_16x16x32_bf16(a1, b0, acc[1][0], 0, 0, 0);
        acc[1][1] = __builtin_amdgcn_mfma_f32_16x16x32_bf16(a1, b1, acc[1][1], 0, 0, 0);
    }

#pragma unroll
    for (int nt = 0; nt < 2; ++nt) {
        const int n = n0 + nt * 16 + lm;
        const bool nval = (n < D);
        const float bv = nval ? bvec[n] : 0.f;
#pragma unroll
        for (int mt = 0; mt < 2; ++mt) {
#pragma unroll
            for (int r = 0; r < 4; ++r) {
                const int m = m0 + mt * 16 + quad * 4 + r;
                float y = acc[mt][nt][r] + bv;
                float g = 1.f / (1.f + __expf(-y));
                float o = 0.f;
                if (nval) {
                    float xo = xf32[(size_t)m * D + n];
                    o = g * fmaxf(y, 0.f) + (1.f - g) * xo;
                    out[(size_t)m * D + n] = o;
                }
                if (n < DP)
                    outb16[(size_t)m * DP + n] = f2b(nval ? o : 0.f);
            }
        }
    }
}

// ---------------- kernel 3a: attention prep (16 j-rows/block, XCD-affine siblings) ----------------
#define PXS 496   // LDS row stride for transpose tile (16B-aligned rows)

__global__ __launch_bounds__(256) void attn_prep_kernel(
    const float* __restrict__ xf32, const ushort_t* __restrict__ xb16,
    const float* __restrict__ attn_w, int layer,
    ushort_t* __restrict__ xw3, ushort_t* __restrict__ xT,
    float* __restrict__ s1g, float* __restrict__ s2g)
{
    __shared__ ushort_t Xs[16 * PXS];   // 15872 B

    // same swizzle as attn core: siblings of one bh land on one XCD (same as highway's my XCD)
    const int bx  = blockIdx.x;
    const int wid = (bx & 7) * 64 + (bx >> 3);
    const int bh  = wid >> 2, jq = wid & 3;
    const int tid = threadIdx.x;
    const int wv  = tid >> 6;
    const int lane = tid & 63;
    const size_t tok0 = (size_t)bh * 64 + jq * 16;

    const float* wb = attn_w + (size_t)layer * 3 * D;   // w1 | w2 | w3
    const float* w3 = wb + 2 * D;

    // stage bf16 rows into LDS + emit xw3 (from f32)
#pragma unroll 1
    for (int c = tid; c < 16 * 60; c += 256) {
        const int j  = c / 60, k8 = c - j * 60;
        const int k0 = k8 * 8;
        bf16x8 v = *(const bf16x8*)&xb16[(tok0 + j) * DP + k0];
        *(bf16x8*)&Xs[j * PXS + k0] = v;
        const float* xr = xf32 + (tok0 + j) * D;
        bf16x8 pk;
#pragma unroll
        for (int t = 0; t < 8; ++t) {
            const int k = k0 + t;
            float p = (k < D) ? xr[k] * w3[k] : 0.f;
            pk[t] = (short)f2b(p);
        }
        *(bf16x8*)&xw3[(tok0 + j) * DP + k0] = pk;
    }

    // s1/s2 dots: 4 rows per wave
#pragma unroll 1
    for (int rr = 0; rr < 4; ++rr) {
        const int j = wv * 4 + rr;
        const float* xr = xf32 + (tok0 + j) * D;
        float a1 = 0.f, a2 = 0.f;
#pragma unroll
        for (int t = 0; t < 8; ++t) {
            const int k = lane + t * 64;
            if (k < D) {
                float xv = xr[k];
                a1 = fmaf(xv, wb[k], a1);
                a2 = fmaf(xv, wb[D + k], a2);
            }
        }
        a1 = wave_sum(a1);
        a2 = wave_sum(a2);
        if (lane == 0) { s1g[tok0 + j] = a1; s2g[tok0 + j] = a2; }
    }
    __syncthreads();

    // transposed emit: packed u32 (two j per word, two d rows per iter)
#pragma unroll 1
    for (int c = tid; c < 240 * 8; c += 256) {
        const int d2 = c >> 3, jp = (c & 7) * 2;
        unsigned r0 = *(const unsigned*)&Xs[jp * PXS + d2 * 2];
        unsigned r1 = *(const unsigned*)&Xs[(jp + 1) * PXS + d2 * 2];
        unsigned lo = (r0 & 0xFFFFu) | (r1 << 16);
        unsigned hi = (r0 >> 16) | (r1 & 0xFFFF0000u);
        ushort_t* dst = xT + ((size_t)bh * 480 + d2 * 2) * 64 + jq * 16 + jp;
        *(unsigned*)dst        = lo;
        *(unsigned*)(dst + 64) = hi;
    }
}

// ---------------- kernel 3b: attention core (tiny LDS, grid 512) ----------------
#define ALS 72    // P LDS row stride (bf16)

template <bool RES_EMIT>
__global__ __launch_bounds__(256) void attn_fused_kernel(
    const float* __restrict__ xf32, const ushort_t* __restrict__ xb16,
    const ushort_t* __restrict__ xw3, const ushort_t* __restrict__ xT,
    const float* __restrict__ s1g, const float* __restrict__ s2g,
    const int* __restrict__ q1_len, const int* __restrict__ q2_len,
    const float* __restrict__ attn_b, int layer,
    float* __restrict__ outf, ushort_t* __restrict__ outb16)
{
    __shared__ float    sc[16][68];   // masked scores, 4352 B
    __shared__ ushort_t Al[16 * ALS]; // P (bf16), 2304 B

    // XCD swizzle: 4 sibling blocks of one bh share an XCD's L2 (512 % 8 == 0).
    const int bx  = blockIdx.x;
    const int wid = (bx & 7) * 64 + (bx >> 3);
    const int bh  = wid >> 2, iq = wid & 3;
    const int branch = bh >> 6, b = bh & 63;
    const int tid  = threadIdx.x;
    const int wv   = tid >> 6;
    const int lane = tid & 63;
    const int ln   = lane & 15, quad = lane >> 4;
    const int i0   = iq * 16;

    // ---- QK^T: wave wv computes scores[16 i][16 j] for j-tile wv ----
    // 2 k-interleaved accumulators break the 15-long dependent MFMA chain.
    const ushort_t* xa = xb16 + ((size_t)bh * 64 + i0 + ln) * DP + quad * 8;
    const ushort_t* xb = xw3  + ((size_t)bh * 64 + wv * 16 + ln) * DP + quad * 8;

    f32x4 qa0 = (f32x4){0.f, 0.f, 0.f, 0.f};
    f32x4 qa1 = (f32x4){0.f, 0.f, 0.f, 0.f};
#pragma unroll
    for (int ks = 0; ks < 14; ks += 2) {
        bf16x8 a0 = *(const bf16x8*)(xa + ks * 32);
        bf16x8 b0 = *(const bf16x8*)(xb + ks * 32);
        bf16x8 a1 = *(const bf16x8*)(xa + ks * 32 + 32);
        bf16x8 b1 = *(const bf16x8*)(xb + ks * 32 + 32);
        qa0 = __builtin_amdgcn_mfma_f32_16x16x32_bf16(a0, b0, qa0, 0, 0, 0);
        qa1 = __builtin_amdgcn_mfma_f32_16x16x32_bf16(a1, b1, qa1, 0, 0, 0);
    }
    {
        bf16x8 a = *(const bf16x8*)(xa + 14 * 32);
        bf16x8 bq = *(const bf16x8*)(xb + 14 * 32);
        qa0 = __builtin_amdgcn_mfma_f32_16x16x32_bf16(a, bq, qa0, 0, 0, 0);
    }
    f32x4 qacc = qa0 + qa1;

    const int   len  = (branch ? q2_len : q1_len)[b];
    const float bias = attn_b[layer];
    const int   j    = wv * 16 + ln;
    const float s2v  = s2g[bh * 64 + j];
#pragma unroll
    for (int reg = 0; reg < 4; ++reg) {
        const int i = i0 + quad * 4 + reg;
        float v = qacc[reg] + s1g[bh * 64 + i] + s2v + bias;
        if (j >= len) v = -1e-9f;        // reference's (buggy) mask value
        sc[quad * 4 + reg][j] = v;
    }
    __syncthreads();

    // ---- softmax: wave wv handles local rows wv*4..wv*4+3, full 64-lane row ----
#pragma unroll
    for (int rr = 0; rr < 4; ++rr) {
        const int r = wv * 4 + rr;
        float v = sc[r][lane];
        float m = v;
#pragma unroll
        for (int o = 32; o; o >>= 1) m = fmaxf(m, __shfl_xor(m, o, 64));
        float ev = __expf(v - m);
        float sm = ev;
#pragma unroll
        for (int o = 32; o; o >>= 1) sm += __shfl_xor(sm, o, 64);
        Al[r * ALS + lane] = f2b(ev * (1.f / sm));
    }
    __syncthreads();

    // ---- AV: out[i][d] = sum_j P[i][j] X[j][d]; d-tiles round-robin over waves ----
    const ushort_t* xTb = xT + (size_t)bh * 480 * 64;
    bf16x8 af0 = *(const bf16x8*)&Al[ln * ALS + quad * 8];
    bf16x8 af1 = *(const bf16x8*)&Al[ln * ALS + quad * 8 + 32];

#pragma unroll 2
    for (int dt = wv; dt < 30; dt += 4) {
        bf16x8 b0 = *(const bf16x8*)&xTb[(size_t)(dt * 16 + ln) * 64 + quad * 8];
        bf16x8 b1 = *(const bf16x8*)&xTb[(size_t)(dt * 16 + ln) * 64 + quad * 8 + 32];
        f32x4 acc = (f32x4){0.f, 0.f, 0.f, 0.f};
        acc = __builtin_amdgcn_mfma_f32_16x16x32_bf16(af0, b0, acc, 0, 0, 0);
        acc = __builtin_amdgcn_mfma_f32_16x16x32_bf16(af1, b1, acc, 0, 0, 0);

        const int d = dt * 16 + ln;
        if (d < D) {
#pragma unroll
            for (int reg = 0; reg < 4; ++reg) {
                const int i = i0 + quad * 4 + reg;
                float v = acc[reg];
                if (RES_EMIT) v += xf32[((size_t)bh * 64 + i) * D + d];
                outf[((size_t)bh * 64 + i) * D + d] = v;
                if (RES_EMIT)
                    outb16[((size_t)bh * 64 + i) * DP + d] = f2b(v);
            }
        }
    }
}

// ---------------- launch ----------------
extern "C" void kernel_launch(void* const* d_in, const int* in_sizes, int n_in,
                              void* d_out, int out_size, void* d_ws, size_t ws_size,
                              hipStream_t stream) {
    const int*   q1       = (const int*)  d_in[0];
    const int*   q2       = (const int*)  d_in[1];
    const int*   q1_len   = (const int*)  d_in[2];
    const int*   q2_len   = (const int*)  d_in[3];
    const int*   q1c      = (const int*)  d_in[4];
    const int*   q2c      = (const int*)  d_in[5];
    const float* word_emb = (const float*)d_in[6];
    const float* char_emb = (const float*)d_in[7];
    const float* w3       = (const float*)d_in[8];
    const float* b3       = (const float*)d_in[9];
    const float* w4       = (const float*)d_in[10];
    const float* b4       = (const float*)d_in[11];
    const float* w5       = (const float*)d_in[12];
    const float* b5       = (const float*)d_in[13];
    const float* hw_w     = (const float*)d_in[14];
    const float* hw_b     = (const float*)d_in[15];
    const float* attn_w   = (const float*)d_in[16];
    const float* attn_b   = (const float*)d_in[17];
    float* out = (float*)d_out;

    float*    buf0    = (float*)d_ws;                          // 2*NT*D f32
    float*    buf1    = buf0 + (size_t)2 * NT * D;             // 2*NT*D f32
    float*    bias160 = buf1 + (size_t)2 * NT * D;             // 160 f32
    ushort_t* xb16a   = (ushort_t*)(bias160 + 160);            // 2*NT*DP bf16
    ushort_t* xb16b   = xb16a + (size_t)2 * NT * DP;           // 2*NT*DP bf16
    ushort_t* Wb16    = xb16b + (size_t)2 * NT * DP;           // 512*DP bf16
    ushort_t* Wpad    = Wb16 + (size_t)512 * DP;               // 160*320 bf16
    ushort_t* ceb16   = Wpad + (size_t)160 * 320;              // 100*64 bf16
    ushort_t* xw3     = ceb16 + (size_t)100 * 64;              // 2*NT*DP bf16
    ushort_t* xTb     = xw3 + (size_t)2 * NT * DP;             // 128*480*64 bf16 (== 2*NT*DP)
    float*    s1g     = (float*)(xTb + (size_t)2 * NT * DP);   // 2*NT f32
    float*    s2g     = s1g + (size_t)2 * NT;                  // 2*NT f32

    // 1. fused weight prep + fused embed/conv
    prep_kernel<<<(512 * DP + 160 * 320 + 160 + 100 * 64 + 255) / 256, 256, 0, stream>>>(
        hw_w, w3, b3, w4, b4, w5, b5, char_emb, Wb16, Wpad, bias160, ceb16);
    embed_conv_kernel<<<1024, 256, 0, stream>>>(q1, q2, q1c, q2c, word_emb, ceb16,
                                                Wpad, bias160, buf0, xb16a);

    // 2. highway x2 via MFMA (XCD-affine 1-D grid)
    highway_mfma_kernel<<<1024, 256, 0, stream>>>(xb16a, buf0, Wb16, hw_b, buf1, xb16b);
    highway_mfma_kernel<<<1024, 256, 0, stream>>>(xb16b, buf1, Wb16, hw_b, buf0, xb16a);

    // 3. attn layer 0: prep from buf0/xb16a, core -> buf1/xb16b (residual fused)
    attn_prep_kernel<<<512, 256, 0, stream>>>(buf0, xb16a, attn_w, 0, xw3, xTb, s1g, s2g);
    attn_fused_kernel<true><<<512, 256, 0, stream>>>(
        buf0, xb16a, xw3, xTb, s1g, s2g, q1_len, q2_len, attn_b, 0, buf1, xb16b);

    // 4. attn layer 1: prep from buf1/xb16b, core -> d_out (f32 only)
    attn_prep_kernel<<<512, 256, 0, stream>>>(buf1, xb16b, attn_w, 1, xw3, xTb, s1g, s2g);
    attn_fused_kernel<false><<<512, 256, 0, stream>>>(
        buf1, xb16b, xw3, xTb, s1g, s2g, q1_len, q2_len, attn_b, 1, out, nullptr);
}